// Round 1
// baseline (103.631 us; speedup 1.0000x reference)
//
#include <hip/hip_runtime.h>
#include <hip/hip_bf16.h>

// Problem constants
#define B_ 2
#define N_ 48
#define H_ 256
#define NH_ 8
#define DH_ 32

typedef __attribute__((ext_vector_type(8))) short bf16x8;
typedef __attribute__((ext_vector_type(4))) float f32x4;

__device__ __forceinline__ unsigned short f2bf(float f) {
  unsigned u = __float_as_uint(f);
  u += 0x7FFFu + ((u >> 16) & 1u);
  return (unsigned short)(u >> 16);
}

// ---------------------------------------------------------------------------
// P0: pack [Wq|Wk|Wv] (256x768) and [Wsq|Wsk|Wsv] (256x96) into bf16 MFMA
// B-fragment order: frag[nt][kt][lane][i] = W[kt*32 + (lane>>4)*8 + i][nt*16 + (lane&15)]
// plus biascat768 = [bq|bk|bv].
// ---------------------------------------------------------------------------
__global__ void pack_kernel(const float* __restrict__ Wq, const float* __restrict__ Wk,
                            const float* __restrict__ Wv, const float* __restrict__ bq,
                            const float* __restrict__ bk, const float* __restrict__ bv,
                            const float* __restrict__ Wsq, const float* __restrict__ Wsk,
                            const float* __restrict__ Wsv,
                            unsigned short* __restrict__ wfrag_pair,
                            unsigned short* __restrict__ wfrag_main,
                            float* __restrict__ biascat) {
  int t = blockIdx.x * 256 + threadIdx.x;
  if (t < 196608) {  // 48 ntiles * 8 ktiles * 64 lanes * 8
    int i8 = t & 7, lane = (t >> 3) & 63, kt = (t >> 9) & 7, nt = t >> 12;
    int k = kt * 32 + ((lane >> 4) << 3) + i8;
    int n = nt * 16 + (lane & 15);
    const float* W = (n < 256) ? Wq : (n < 512) ? Wk : Wv;
    wfrag_pair[t] = f2bf(W[k * 256 + (n & 255)]);
  } else if (t < 196608 + 24576) {  // 6 ntiles * 8 * 64 * 8
    int p = t - 196608;
    int i8 = p & 7, lane = (p >> 3) & 63, kt = (p >> 9) & 7, nt = p >> 12;
    int k = kt * 32 + ((lane >> 4) << 3) + i8;
    int n = nt * 16 + (lane & 15);  // 0..95
    const float* W = (n < 32) ? Wsq : (n < 64) ? Wsk : Wsv;
    wfrag_main[p] = f2bf(W[k * 32 + (n & 31)]);
  } else if (t < 196608 + 24576 + 768) {
    int p = t - 196608 - 24576;
    const float* bsrc = (p < 256) ? bq : (p < 512) ? bk : bv;
    biascat[p] = bsrc[p & 255];
  }
}

// ---------------------------------------------------------------------------
// Shared helpers: stage a 48x256 f32 tile -> bf16 LDS (XOR-swizzled rows),
// and the 48x(16-col strip) MFMA GEMM over K=256.
// Swizzle: byte_off = row*512 + col*2, off ^= (row&7)<<4  (applied both sides)
// ---------------------------------------------------------------------------
__device__ __forceinline__ void stage48x256(const float* __restrict__ src, char* tAc, int tid) {
#pragma unroll
  for (int it = 0; it < 4; ++it) {
    int c = it * 384 + tid;  // 16-byte bf16 chunk id, 0..1535
    const float4* g = reinterpret_cast<const float4*>(src) + (c << 1);
    float4 x = g[0];
    float4 y = g[1];
    int row = c >> 5;
    int off = (row << 9) + ((c & 31) << 4);
    off ^= (row & 7) << 4;
    union { unsigned short us[8]; bf16x8 v; } o;
    o.us[0] = f2bf(x.x); o.us[1] = f2bf(x.y); o.us[2] = f2bf(x.z); o.us[3] = f2bf(x.w);
    o.us[4] = f2bf(y.x); o.us[5] = f2bf(y.y); o.us[6] = f2bf(y.z); o.us[7] = f2bf(y.w);
    *reinterpret_cast<bf16x8*>(tAc + off) = o.v;
  }
}

__device__ __forceinline__ void gemm48xK(const char* tAc, const bf16x8* wf, f32x4 acc[3], int lane) {
#pragma unroll
  for (int kt = 0; kt < 8; ++kt) {
#pragma unroll
    for (int mt = 0; mt < 3; ++mt) {
      int row = mt * 16 + (lane & 15);
      int off = (row << 9) + (kt << 6) + ((lane >> 4) << 4);
      off ^= (row & 7) << 4;
      bf16x8 a = *reinterpret_cast<const bf16x8*>(tAc + off);
      acc[mt] = __builtin_amdgcn_mfma_f32_16x16x32_bf16(a, wf[kt], acc[mt], 0, 0, 0);
    }
  }
}

// ---------------------------------------------------------------------------
// A: pair projections.  proj[(b*48+i)*48+j][0:256]=q, [256:512]=k, [512:768]=v
// grid = 96 row-groups * 8 col-groups; 6 waves, wave w -> ntile (gn*6+w)
// ---------------------------------------------------------------------------
__global__ __launch_bounds__(384, 3)
void pair_proj_kernel(const float* __restrict__ pair,
                      const unsigned short* __restrict__ wfrag_pair,
                      const float* __restrict__ biascat, float* __restrict__ proj) {
  __shared__ __align__(16) char tAc[48 * 256 * 2];
  int tid = threadIdx.x;
  int lane = tid & 63;
  int wave = tid >> 6;
  int gm = blockIdx.x >> 3;  // (b,i) group: 48 rows
  int gn = blockIdx.x & 7;   // 96-col group

  stage48x256(pair + (size_t)gm * 12288, tAc, tid);

  bf16x8 wf[8];
  {
    const bf16x8* wp = reinterpret_cast<const bf16x8*>(wfrag_pair);
#pragma unroll
    for (int kt = 0; kt < 8; ++kt) wf[kt] = wp[((gn * 6 + wave) * 8 + kt) * 64 + lane];
  }
  __syncthreads();

  f32x4 acc[3];
#pragma unroll
  for (int mt = 0; mt < 3; ++mt) acc[mt] = (f32x4){0.f, 0.f, 0.f, 0.f};
  gemm48xK(tAc, wf, acc, lane);

  int col = gn * 96 + wave * 16 + (lane & 15);
  float bias = biascat[col];
  int jb = (lane >> 4) * 4;
#pragma unroll
  for (int mt = 0; mt < 3; ++mt) {
#pragma unroll
    for (int rr = 0; rr < 4; ++rr) {
      int j = mt * 16 + jb + rr;
      proj[(size_t)(gm * 48 + j) * 768 + col] = acc[mt][rr] + bias;
    }
  }
}

// ---------------------------------------------------------------------------
// Main: one block per (b,i,k).  Stage t[b,i,k,:,:] (48x256) -> bf16 LDS,
// GEMM -> sq|sk|sv (48x96, transposed in LDS as [96][49] f32, +bias),
// then f32 scores (8h x 48j), wave-shuffle softmax, PV, write out.
// ---------------------------------------------------------------------------
__global__ __launch_bounds__(384, 3)
void e2e_main(const float* __restrict__ mask, const float* __restrict__ trip,
              const float* __restrict__ proj, const unsigned short* __restrict__ wfragm,
              const float* __restrict__ bsq, const float* __restrict__ bsk,
              const float* __restrict__ bsv, float* __restrict__ out) {
  __shared__ __align__(16) char tAc[48 * 256 * 2];  // 24576 B
  __shared__ float sqT[96][49];                     // [n][j], n: 0-31 sq, 32-63 sk, 64-95 sv
  __shared__ float khl[256];
  __shared__ float maskl[48];
  __shared__ float pbuf[8][48];

  int tid = threadIdx.x;
  int lane = tid & 63;
  int wave = tid >> 6;

  // XCD-bijective swizzle: 4608 = 8 * 576, keep same-(b,i) blocks on one XCD
  int bid0 = blockIdx.x;
  int wg = (bid0 & 7) * 576 + (bid0 >> 3);  // (b*48+i)*48 + k
  int b = wg / 2304;
  int r0 = wg % 2304;
  int k = r0 % 48;
  int rowbase = wg - k;  // proj row of (b,i,j=0)

  stage48x256(trip + (size_t)wg * 12288, tAc, tid);

  bf16x8 wf[8];
  {
    const bf16x8* wp = reinterpret_cast<const bf16x8*>(wfragm);
#pragma unroll
    for (int kt = 0; kt < 8; ++kt) wf[kt] = wp[(wave * 8 + kt) * 64 + lane];
  }
  if (tid < 256) khl[tid] = proj[(size_t)wg * 768 + 256 + tid];
  if (tid < 48) maskl[tid] = mask[(b * 48 + k) * 48 + tid];
  __syncthreads();

  f32x4 acc[3];
#pragma unroll
  for (int mt = 0; mt < 3; ++mt) acc[mt] = (f32x4){0.f, 0.f, 0.f, 0.f};
  gemm48xK(tAc, wf, acc, lane);

  // epilogue: sqT[n][j] = acc + bias  (wave w owns n = w*16 .. w*16+15)
  {
    int n = wave * 16 + (lane & 15);
    const float* bp = (n < 32) ? bsq : (n < 64) ? bsk : bsv;
    float bias = bp[n & 31];
    int jb = (lane >> 4) * 4;
#pragma unroll
    for (int mt = 0; mt < 3; ++mt) {
#pragma unroll
      for (int rr = 0; rr < 4; ++rr) sqT[n][mt * 16 + jb + rr] = acc[mt][rr] + bias;
    }
  }
  __syncthreads();

  // scores: 384 threads = 8h x 48j, f32
  {
    int j = tid % 48;
    int h = tid / 48;
    const float4* q4 = reinterpret_cast<const float4*>(proj + (size_t)(rowbase + j) * 768 + h * 32);
    float s = 0.f;
#pragma unroll
    for (int d4 = 0; d4 < 8; ++d4) {
      float4 q = q4[d4];
      int d = d4 * 4;
      s += (q.x + sqT[d + 0][j]) * (khl[h * 32 + d + 0] + sqT[32 + d + 0][j]);
      s += (q.y + sqT[d + 1][j]) * (khl[h * 32 + d + 1] + sqT[32 + d + 1][j]);
      s += (q.z + sqT[d + 2][j]) * (khl[h * 32 + d + 2] + sqT[32 + d + 2][j]);
      s += (q.w + sqT[d + 3][j]) * (khl[h * 32 + d + 3] + sqT[32 + d + 3][j]);
    }
    pbuf[h][j] = s * 0.17677669529663687f + maskl[j];  // 1/sqrt(32)
  }
  __syncthreads();

  // softmax over j per (h): waves 0..5 take rows wave, wave+6
  for (int h = wave; h < 8; h += 6) {
    float x = (lane < 48) ? pbuf[h][lane] : -INFINITY;
    float m = x;
#pragma unroll
    for (int off = 32; off; off >>= 1) m = fmaxf(m, __shfl_xor(m, off));
    float e = (lane < 48) ? __expf(x - m) : 0.f;
    float sum = e;
#pragma unroll
    for (int off = 32; off; off >>= 1) sum += __shfl_xor(sum, off);
    if (lane < 48) pbuf[h][lane] = e / sum;
  }
  __syncthreads();

  // PV: 256 threads = (h,d); v = proj_v[b,i,j, h*32+d] + sv0[j][d]
  if (tid < 256) {
    int h = tid >> 5, d = tid & 31;
    const float* vbase = proj + (size_t)rowbase * 768 + 512 + tid;
    float a = 0.f;
#pragma unroll 4
    for (int j = 0; j < 48; ++j) a += pbuf[h][j] * (vbase[(size_t)j * 768] + sqT[64 + d][j]);
    out[(size_t)wg * 256 + tid] = a;
  }
}

// ---------------------------------------------------------------------------
extern "C" void kernel_launch(void* const* d_in, const int* in_sizes, int n_in,
                              void* d_out, int out_size, void* d_ws, size_t ws_size,
                              hipStream_t stream) {
  const float* mask = (const float*)d_in[0];
  const float* pair = (const float*)d_in[1];
  const float* trip = (const float*)d_in[2];
  const float* Wq = (const float*)d_in[3];
  const float* bq = (const float*)d_in[4];
  const float* Wk = (const float*)d_in[5];
  const float* bk = (const float*)d_in[6];
  const float* Wv = (const float*)d_in[7];
  const float* bv = (const float*)d_in[8];
  const float* Wsq = (const float*)d_in[9];
  const float* bsq = (const float*)d_in[10];
  const float* Wsk = (const float*)d_in[11];
  const float* bsk = (const float*)d_in[12];
  const float* Wsv = (const float*)d_in[13];
  const float* bsv = (const float*)d_in[14];

  char* ws = (char*)d_ws;
  float* proj = (float*)ws;                                               // 14,155,776 B
  unsigned short* wfrag_pair = (unsigned short*)(ws + 14155776);          // 393,216 B
  unsigned short* wfrag_main = (unsigned short*)(ws + 14155776 + 393216); // 49,152 B
  float* biascat = (float*)(ws + 14155776 + 393216 + 49152);              // 3,072 B

  pack_kernel<<<867, 256, 0, stream>>>(Wq, Wk, Wv, bq, bk, bv, Wsq, Wsk, Wsv,
                                       wfrag_pair, wfrag_main, biascat);
  pair_proj_kernel<<<768, 384, 0, stream>>>(pair, wfrag_pair, biascat, proj);
  e2e_main<<<4608, 384, 0, stream>>>(mask, trip, proj, wfrag_main, bsq, bsk, bsv,
                                     (float*)d_out);
}